// Round 1
// baseline (6573.033 us; speedup 1.0000x reference)
//
#include <hip/hip_runtime.h>
#include <hip/hip_bf16.h>
#include <stdint.h>

// ---------------------------------------------------------------------------
// S4 / Conformer-style encoder, 6 layers. B=8 T=2048 D=512 F=2048 N=64 K=31
// Residual stream x kept fp32 in ws; GEMMs in bf16 MFMA (16x16x32), fp32 acc.
// DSS causal conv done exactly via the diagonal-SSM recurrence (wave scan).
// ---------------------------------------------------------------------------

#define NL 6
#define TT 2048
#define BB 8
#define DD 512
#define FF 2048
#define ROWS (BB*TT)          // 16384

typedef __attribute__((ext_vector_type(4))) float f32x4;
typedef __attribute__((ext_vector_type(8))) short s16x8;

#define DEVI __device__ __forceinline__

DEVI float bf2f(uint32_t u) { union { uint32_t i; float f; } v; v.i = u << 16; return v.f; }
DEVI uint16_t f2bf(float f) {
    union { float f; uint32_t i; } v; v.f = f;
    uint32_t x = v.i;
    return (uint16_t)((x + 0x7fffu + ((x >> 16) & 1u)) >> 16);   // RNE
}
DEVI float gelu_f(float x) {   // tanh-approx gelu (jax.nn.gelu default)
    float x3 = x * x * x;
    float a  = 0.7978845608028654f * (x + 0.044715f * x3);
    float e  = __expf(2.0f * a);
    float t  = 1.0f - 2.0f / (e + 1.0f);
    return 0.5f * x * (1.0f + t);
}
DEVI float sigm(float x) { return 1.0f / (1.0f + __expf(-x)); }

// ---------------- weight prep ----------------------------------------------
// fp32 [L][K][N] -> bf16 [L][N][K]
__global__ void k_wtrans(const float* __restrict__ src, uint16_t* __restrict__ dst,
                         int K, int N) {
    __shared__ float tile[32][33];
    int l = blockIdx.z;
    const float* s = src + (size_t)l * K * N;
    uint16_t*    d = dst + (size_t)l * N * K;
    int n0 = blockIdx.x * 32, k0 = blockIdx.y * 32;
    int tx = threadIdx.x, ty = threadIdx.y;
#pragma unroll
    for (int i = 0; i < 4; i++) {
        int k = k0 + ty + i * 8;
        tile[ty + i * 8][tx] = s[(size_t)k * N + n0 + tx];
    }
    __syncthreads();
#pragma unroll
    for (int i = 0; i < 4; i++) {
        int n = n0 + ty + i * 8;
        d[(size_t)n * K + k0 + tx] = f2bf(tile[tx][ty + i * 8]);
    }
}
// fp32 -> bf16 same layout
__global__ void k_wcvt(const float* __restrict__ src, uint16_t* __restrict__ dst, int n) {
    int i = blockIdx.x * 256 + threadIdx.x;
    if (i < n) dst[i] = f2bf(src[i]);
}
// dw [L][512][31] -> dwt [L][31][512] fp32
__global__ void k_dwt(const float* __restrict__ dw, float* __restrict__ dwt) {
    int i = blockIdx.x * 256 + threadIdx.x;
    int tot = NL * DD * 31;
    if (i >= tot) return;
    int l = i / (DD * 31), r = i % (DD * 31), d = r / 31, k = r % 31;
    dwt[(size_t)l * 31 * DD + k * DD + d] = dw[i];
}

// ---------------- input projection  src[16384][80] @ W[80][512] -------------
__global__ void k_inproj(const float* __restrict__ src, const float* __restrict__ W,
                         const float* __restrict__ bias, float* __restrict__ X) {
    __shared__ float srow[80];
    int r = blockIdx.x, tid = threadIdx.x;
    if (tid < 80) srow[tid] = src[(size_t)r * 80 + tid];
    __syncthreads();
    int c = tid * 2;
    float a0 = bias[c], a1 = bias[c + 1];
    for (int k = 0; k < 80; k++) {
        float s = srow[k];
        const float2 w = *(const float2*)(W + (size_t)k * DD + c);
        a0 = fmaf(s, w.x, a0);
        a1 = fmaf(s, w.y, a1);
    }
    float2* px = (float2*)(X + (size_t)r * DD + c);
    *px = make_float2(a0, a1);
}

// ---------------- LayerNorm (wave per row, row = 512 f32) -------------------
// MODE 0: ->bf16   1: gelu->bf16   2: ->f32   3: ->f32 + speaker (final)
template <int MODE>
__global__ void k_ln(const float* __restrict__ in, void* __restrict__ outp,
                     const float* __restrict__ gam, const float* __restrict__ bet,
                     const float* __restrict__ spk, float eps) {
    int row  = blockIdx.x * 4 + (threadIdx.x >> 6);
    int lane = threadIdx.x & 63;
    const float* x = in + (size_t)row * DD;
    float4 a0 = *(const float4*)&x[lane * 4];
    float4 a1 = *(const float4*)&x[256 + lane * 4];
    float v[8] = {a0.x, a0.y, a0.z, a0.w, a1.x, a1.y, a1.z, a1.w};
    float s = 0.f, q = 0.f;
#pragma unroll
    for (int i = 0; i < 8; i++) { s += v[i]; q += v[i] * v[i]; }
#pragma unroll
    for (int m = 1; m < 64; m <<= 1) { s += __shfl_xor(s, m); q += __shfl_xor(q, m); }
    float mean = s * (1.0f / 512.0f);
    float var  = fmaxf(q * (1.0f / 512.0f) - mean * mean, 0.0f);
    float inv  = rsqrtf(var + eps);
    float4 g0 = *(const float4*)&gam[lane * 4];
    float4 g1 = *(const float4*)&gam[256 + lane * 4];
    float4 b0 = *(const float4*)&bet[lane * 4];
    float4 b1 = *(const float4*)&bet[256 + lane * 4];
    float gv[8] = {g0.x, g0.y, g0.z, g0.w, g1.x, g1.y, g1.z, g1.w};
    float bv[8] = {b0.x, b0.y, b0.z, b0.w, b1.x, b1.y, b1.z, b1.w};
    float y[8];
#pragma unroll
    for (int i = 0; i < 8; i++) y[i] = (v[i] - mean) * inv * gv[i] + bv[i];
    if (MODE == 1) {
#pragma unroll
        for (int i = 0; i < 8; i++) y[i] = gelu_f(y[i]);
    }
    if (MODE == 0 || MODE == 1) {
        uint16_t* o = (uint16_t*)outp + (size_t)row * DD;
        uint2 p0, p1;
        p0.x = (uint32_t)f2bf(y[0]) | ((uint32_t)f2bf(y[1]) << 16);
        p0.y = (uint32_t)f2bf(y[2]) | ((uint32_t)f2bf(y[3]) << 16);
        p1.x = (uint32_t)f2bf(y[4]) | ((uint32_t)f2bf(y[5]) << 16);
        p1.y = (uint32_t)f2bf(y[6]) | ((uint32_t)f2bf(y[7]) << 16);
        *(uint2*)&o[lane * 4]       = p0;
        *(uint2*)&o[256 + lane * 4] = p1;
    } else {
        float* o = (float*)outp + (size_t)row * DD;
        if (MODE == 3) {
            const float* sp = spk + (size_t)(row >> 11) * DD;
            float4 s0 = *(const float4*)&sp[lane * 4];
            float4 s1 = *(const float4*)&sp[256 + lane * 4];
            y[0] += s0.x; y[1] += s0.y; y[2] += s0.z; y[3] += s0.w;
            y[4] += s1.x; y[5] += s1.y; y[6] += s1.z; y[7] += s1.w;
        }
        *(float4*)&o[lane * 4]       = make_float4(y[0], y[1], y[2], y[3]);
        *(float4*)&o[256 + lane * 4] = make_float4(y[4], y[5], y[6], y[7]);
    }
}

// ---------------- bf16 MFMA GEMM, 128x128 tile, BK=32, 4 waves --------------
// A bf16 [M][K]; Bt bf16 [N][K]  (B transposed).  C = A @ Bt^T + bias.
// MODE 0: gelu->bf16 out[M][N]   1: ->bf16 out[M][N]
//      2: X[M][512] += 0.5*v     3: X += v       4: outf32 = X + 0.5*v
template <int MODE>
__global__ __launch_bounds__(256) void k_gemm(
    const uint16_t* __restrict__ A, const uint16_t* __restrict__ Bt,
    const float* __restrict__ bias, int M, int N, int K,
    void* __restrict__ outp, float* __restrict__ X) {
    __shared__ __align__(16) uint16_t As[128 * 40];
    __shared__ __align__(16) uint16_t Bs[128 * 40];
    int tid = threadIdx.x;
    int m0 = blockIdx.x * 128, n0 = blockIdx.y * 128;
    int wave = tid >> 6, lane = tid & 63;
    int wm = (wave >> 1) * 64, wn = (wave & 1) * 64;
    int l15 = lane & 15, l16 = lane >> 4;

    f32x4 acc[4][4];
#pragma unroll
    for (int i = 0; i < 4; i++)
#pragma unroll
        for (int j = 0; j < 4; j++) acc[i][j] = (f32x4){0.f, 0.f, 0.f, 0.f};

    for (int kt = 0; kt < K; kt += 32) {
#pragma unroll
        for (int i = 0; i < 2; i++) {
            int idx = tid + i * 256;
            int row = idx >> 2, kq = idx & 3;
            uint4 va = *(const uint4*)(A  + (size_t)(m0 + row) * K + kt + kq * 8);
            *(uint4*)&As[row * 40 + kq * 8] = va;
            uint4 vb = *(const uint4*)(Bt + (size_t)(n0 + row) * K + kt + kq * 8);
            *(uint4*)&Bs[row * 40 + kq * 8] = vb;
        }
        __syncthreads();
        s16x8 af[4], bfr[4];
#pragma unroll
        for (int i = 0; i < 4; i++)
            af[i] = *(const s16x8*)&As[(wm + i * 16 + l15) * 40 + l16 * 8];
#pragma unroll
        for (int j = 0; j < 4; j++)
            bfr[j] = *(const s16x8*)&Bs[(wn + j * 16 + l15) * 40 + l16 * 8];
#pragma unroll
        for (int i = 0; i < 4; i++)
#pragma unroll
            for (int j = 0; j < 4; j++)
                acc[i][j] = __builtin_amdgcn_mfma_f32_16x16x32_bf16(af[i], bfr[j], acc[i][j], 0, 0, 0);
        __syncthreads();
    }
    // epilogue: D frag: col = l15, row = l16*4 + q
#pragma unroll
    for (int i = 0; i < 4; i++) {
#pragma unroll
        for (int j = 0; j < 4; j++) {
            int gcol = n0 + wn + j * 16 + l15;
            float bv = bias[gcol];
#pragma unroll
            for (int q = 0; q < 4; q++) {
                int grow = m0 + wm + i * 16 + l16 * 4 + q;
                float v = acc[i][j][q] + bv;
                if (MODE == 0) {
                    ((uint16_t*)outp)[(size_t)grow * N + gcol] = f2bf(gelu_f(v));
                } else if (MODE == 1) {
                    ((uint16_t*)outp)[(size_t)grow * N + gcol] = f2bf(v);
                } else if (MODE == 2) {
                    X[(size_t)grow * DD + gcol] += 0.5f * v;
                } else if (MODE == 3) {
                    X[(size_t)grow * DD + gcol] += v;
                } else {
                    ((float*)outp)[(size_t)grow * DD + gcol] =
                        X[(size_t)grow * DD + gcol] + 0.5f * v;
                }
            }
        }
    }
}

// ---------------- bf16 transpose [R][C] -> [C][R] per batch z ---------------
__global__ void k_tpose(const uint16_t* __restrict__ in, uint16_t* __restrict__ out,
                        int R, int C) {
    __shared__ uint16_t tile[32][33];
    size_t boff = (size_t)blockIdx.z * R * C;
    int c0 = blockIdx.x * 32, r0 = blockIdx.y * 32;
    int tx = threadIdx.x, ty = threadIdx.y;
#pragma unroll
    for (int i = 0; i < 4; i++)
        tile[ty + i * 8][tx] = in[boff + (size_t)(r0 + ty + i * 8) * C + c0 + tx];
    __syncthreads();
#pragma unroll
    for (int i = 0; i < 4; i++)
        out[boff + (size_t)(c0 + ty + i * 8) * R + r0 + tx] = tile[tx][ty + i * 8];
}

// ---------------- DSS sequential scan: wave per (b,h), lane = pole n --------
__global__ __launch_bounds__(64) void k_scan(
    const uint16_t* __restrict__ u, uint16_t* __restrict__ y,
    const float* __restrict__ lam_re, const float* __restrict__ lam_im,
    const float* __restrict__ c_re, const float* __restrict__ c_im,
    const float* __restrict__ log_dt) {
    int bh   = blockIdx.x;           // b*512 + h
    int h    = bh & (DD - 1);
    int lane = threadIdx.x;
    float dt = expf(log_dt[0]);
    float lr = lam_re[lane], li = lam_im[lane];
    float mag = expf(-expf(lr) * dt);
    float th  = li * dt;
    float Are = mag * cosf(th), Aim = mag * sinf(th);
    float Cre = c_re[(size_t)h * 64 + lane] * dt;
    float Cim = c_im[(size_t)h * 64 + lane] * dt;
    const uint16_t* ur = u + (size_t)bh * TT;
    uint16_t*       yr = y + (size_t)bh * TT;
    float sre = 0.f, sim = 0.f;
    for (int t0 = 0; t0 < TT; t0 += 64) {
        float myu = bf2f((uint32_t)ur[t0 + lane]);
        int mybits = __float_as_int(myu);
        float keep = 0.f;
#pragma unroll
        for (int tt = 0; tt < 64; tt++) {
            float uf = __int_as_float(__builtin_amdgcn_readlane(mybits, tt));
            float old_re = sre;
            sre = fmaf(Are, sre, uf);
            sre = fmaf(-Aim, sim, sre);
            float tmp = Aim * old_re;
            sim = fmaf(Are, sim, tmp);
            float p = fmaf(-Cim, sim, Cre * sre);
            p += __shfl_xor(p, 1);  p += __shfl_xor(p, 2);  p += __shfl_xor(p, 4);
            p += __shfl_xor(p, 8);  p += __shfl_xor(p, 16); p += __shfl_xor(p, 32);
            if (lane == tt) keep = p;
        }
        yr[t0 + lane] = f2bf(keep);
    }
}

// ---------------- fused: out[b][t][h] = gelu(y[b][h][t] + d[h]*u[b][h][t]) --
__global__ void k_tgelu(const uint16_t* __restrict__ y, const uint16_t* __restrict__ u,
                        const float* __restrict__ d, uint16_t* __restrict__ out) {
    __shared__ uint16_t tile[32][33];
    int b = blockIdx.z;
    int t0 = blockIdx.x * 32, h0 = blockIdx.y * 32;
    int tx = threadIdx.x, ty = threadIdx.y;
    const uint16_t* yb = y + (size_t)b * DD * TT;
    const uint16_t* ub = u + (size_t)b * DD * TT;
#pragma unroll
    for (int i = 0; i < 4; i++) {
        int h = h0 + ty + i * 8;
        float dv = d[h];
        size_t idx = (size_t)h * TT + t0 + tx;
        float val = gelu_f(bf2f((uint32_t)yb[idx]) + dv * bf2f((uint32_t)ub[idx]));
        tile[ty + i * 8][tx] = f2bf(val);
    }
    __syncthreads();
    uint16_t* ob = out + (size_t)b * TT * DD;
#pragma unroll
    for (int i = 0; i < 4; i++) {
        int t = t0 + ty + i * 8;
        ob[(size_t)t * DD + h0 + tx] = tile[tx][ty + i * 8];
    }
}

// ---------------- GLU: z[16384][1024] -> a*sig(g); SKIP: X += ; else bf16 out
template <int SKIP>
__global__ void k_glu(const uint16_t* __restrict__ z, float* __restrict__ X,
                      uint16_t* __restrict__ out) {
    int i = blockIdx.x * 256 + threadIdx.x;      // over 16384*256  (2 cols each)
    int r = i >> 8;
    int c = (i & 255) * 2;
    uint32_t av = *(const uint32_t*)&z[(size_t)r * 1024 + c];
    uint32_t gv = *(const uint32_t*)&z[(size_t)r * 1024 + 512 + c];
    float a0 = bf2f(av & 0xffffu), a1 = bf2f(av >> 16);
    float g0 = bf2f(gv & 0xffffu), g1 = bf2f(gv >> 16);
    float v0 = a0 * sigm(g0), v1 = a1 * sigm(g1);
    if (SKIP) {
        float2* px = (float2*)&X[(size_t)r * DD + c];
        float2 x = *px;
        x.x += v0; x.y += v1;
        *px = x;
    } else {
        uint32_t p = (uint32_t)f2bf(v0) | ((uint32_t)f2bf(v1) << 16);
        *(uint32_t*)&out[(size_t)r * DD + c] = p;
    }
}

// ---------------- depthwise conv k=31 SAME over t, [B][T][512] --------------
__global__ void k_dwconv(const uint16_t* __restrict__ in, const float* __restrict__ dwt,
                         const float* __restrict__ db, float* __restrict__ out) {
    int i = blockIdx.x * 256 + threadIdx.x;      // over 8*2048*256 (2 ch each)
    int d = (i & 255) * 2;
    int t = (i >> 8) & (TT - 1);
    int b = i >> 19;
    float a0 = db[d], a1 = db[d + 1];
    const uint16_t* ib = in + (size_t)b * TT * DD;
#pragma unroll
    for (int j = 0; j < 31; j++) {
        int tj = t + j - 15;
        if (tj >= 0 && tj < TT) {
            uint32_t v = *(const uint32_t*)&ib[(size_t)tj * DD + d];
            float2 w = *(const float2*)&dwt[j * DD + d];
            a0 = fmaf(bf2f(v & 0xffffu), w.x, a0);
            a1 = fmaf(bf2f(v >> 16), w.y, a1);
        }
    }
    size_t off = ((size_t)b * TT + t) * DD + d;
    *(float2*)&out[off] = make_float2(a0, a1);
}

// ---------------------------------------------------------------------------
extern "C" void kernel_launch(void* const* d_in, const int* in_sizes, int n_in,
                              void* d_out, int out_size, void* d_ws, size_t ws_size,
                              hipStream_t stream) {
    const float* src        = (const float*)d_in[0];
    const float* speaker    = (const float*)d_in[1];
    const float* src_w      = (const float*)d_in[2];
    const float* src_b      = (const float*)d_in[3];
    const float* ffn1_ln_g  = (const float*)d_in[4];
    const float* ffn1_ln_b  = (const float*)d_in[5];
    const float* ffn1_w1    = (const float*)d_in[6];
    const float* ffn1_b1    = (const float*)d_in[7];
    const float* ffn1_w2    = (const float*)d_in[8];
    const float* ffn1_b2    = (const float*)d_in[9];
    const float* norm1_g    = (const float*)d_in[10];
    const float* norm1_b    = (const float*)d_in[11];
    const float* lam_re     = (const float*)d_in[12];
    const float* lam_im     = (const float*)d_in[13];
    const float* c_re       = (const float*)d_in[14];
    const float* c_im       = (const float*)d_in[15];
    const float* ssm_d      = (const float*)d_in[16];
    const float* log_dt     = (const float*)d_in[17];
    const float* dss_out_w  = (const float*)d_in[18];
    const float* dss_out_b  = (const float*)d_in[19];
    const float* conv_ln_g  = (const float*)d_in[20];
    const float* conv_ln_b  = (const float*)d_in[21];
    const float* bneck_w    = (const float*)d_in[22];
    const float* bneck_b    = (const float*)d_in[23];
    const float* dw_w       = (const float*)d_in[24];
    const float* dw_b       = (const float*)d_in[25];
    const float* conv_ln2_g = (const float*)d_in[26];
    const float* conv_ln2_b = (const float*)d_in[27];
    const float* conv_lin_w = (const float*)d_in[28];
    const float* conv_lin_b = (const float*)d_in[29];
    const float* ffn2_ln_g  = (const float*)d_in[30];
    const float* ffn2_ln_b  = (const float*)d_in[31];
    const float* ffn2_w1    = (const float*)d_in[32];
    const float* ffn2_b1    = (const float*)d_in[33];
    const float* ffn2_w2    = (const float*)d_in[34];
    const float* ffn2_b2    = (const float*)d_in[35];
    const float* norm2_g    = (const float*)d_in[36];
    const float* norm2_b    = (const float*)d_in[37];
    const float* final_g    = (const float*)d_in[38];
    const float* final_b    = (const float*)d_in[39];
    (void)in_sizes; (void)n_in; (void)out_size; (void)ws_size;

    // workspace layout (bytes)
    uint8_t* ws = (uint8_t*)d_ws;
    float*    X   = (float*)   (ws + 0);                     // 33554432  f32 [16384][512]
    float*    F0  = (float*)   (ws + 33554432);              // 33554432  f32 [16384][512]
    uint16_t* B1  = (uint16_t*)(ws + 67108864);              // 16777216  bf16 [16384][512]
    uint16_t* B2  = (uint16_t*)(ws + 83886080);              // 16777216  bf16 [B][512][2048] / [16384][512]
    uint16_t* B3  = (uint16_t*)(ws + 100663296);             // 16777216  bf16 [B][512][2048]
    uint16_t* H   = (uint16_t*)(ws + 117440512);             // 67108864  bf16 [16384][2048] / [16384][1024]
    uint16_t* Wf1a= (uint16_t*)(ws + 184549376);             // [L][2048][512]
    uint16_t* Wf1b= (uint16_t*)(ws + 197132288);             // [L][512][2048]
    uint16_t* Wds = (uint16_t*)(ws + 209715200);             // [L][1024][512]
    uint16_t* Wbn = (uint16_t*)(ws + 216006656);             // [L][1024][512]
    uint16_t* Wcl = (uint16_t*)(ws + 222298112);             // [L][512][512]
    uint16_t* Wf2a= (uint16_t*)(ws + 225443840);             // [L][2048][512]
    uint16_t* Wf2b= (uint16_t*)(ws + 238026752);             // [L][512][2048]
    float*    DWT = (float*)   (ws + 250609664);             // [L][31][512] f32

    dim3 tb(32, 8);
    // ---- weight prep (once per launch; deterministic) ----
    k_wtrans<<<dim3(FF/32, DD/32, NL), tb, 0, stream>>>(ffn1_w1, Wf1a, DD, FF);
    k_wtrans<<<dim3(DD/32, FF/32, NL), tb, 0, stream>>>(ffn1_w2, Wf1b, FF, DD);
    k_wtrans<<<dim3(1024/32, DD/32, NL), tb, 0, stream>>>(dss_out_w, Wds, DD, 1024);
    k_wcvt<<<(NL*1024*DD + 255)/256, 256, 0, stream>>>(bneck_w, Wbn, NL*1024*DD);
    k_wcvt<<<(NL*DD*DD + 255)/256, 256, 0, stream>>>(conv_lin_w, Wcl, NL*DD*DD);
    k_wtrans<<<dim3(FF/32, DD/32, NL), tb, 0, stream>>>(ffn2_w1, Wf2a, DD, FF);
    k_wtrans<<<dim3(DD/32, FF/32, NL), tb, 0, stream>>>(ffn2_w2, Wf2b, FF, DD);
    k_dwt<<<(NL*DD*31 + 255)/256, 256, 0, stream>>>(dw_w, DWT);

    // ---- input projection ----
    k_inproj<<<ROWS, 256, 0, stream>>>(src, src_w, src_b, X);

    for (int l = 0; l < NL; l++) {
        // 1. FFN1: x += 0.5 * ffn(x)
        k_ln<0><<<4096, 256, 0, stream>>>(X, B1, ffn1_ln_g + l*DD, ffn1_ln_b + l*DD, nullptr, 1e-5f);
        k_gemm<0><<<dim3(128, 16), 256, 0, stream>>>(B1, Wf1a + (size_t)l*FF*DD, ffn1_b1 + l*FF,
                                                     ROWS, FF, DD, H, nullptr);
        k_gemm<2><<<dim3(128, 4), 256, 0, stream>>>(H, Wf1b + (size_t)l*DD*FF, ffn1_b2 + l*DD,
                                                    ROWS, DD, FF, nullptr, X);
        // 2. DSS:  skip = x;  x = glu(dss(ln(x))) + skip
        k_ln<0><<<4096, 256, 0, stream>>>(X, B1, norm1_g + l*DD, norm1_b + l*DD, nullptr, 1e-5f);
        k_tpose<<<dim3(DD/32, TT/32, BB), tb, 0, stream>>>(B1, B2, TT, DD);     // u [B][512][2048]
        k_scan<<<BB*DD, 64, 0, stream>>>(B2, B3, lam_re + l*64, lam_im + l*64,
                                         c_re + (size_t)l*DD*64, c_im + (size_t)l*DD*64, log_dt + l);
        k_tgelu<<<dim3(TT/32, DD/32, BB), tb, 0, stream>>>(B3, B2, ssm_d + l*DD, B1);
        k_gemm<1><<<dim3(128, 8), 256, 0, stream>>>(B1, Wds + (size_t)l*1024*DD, dss_out_b + l*1024,
                                                    ROWS, 1024, DD, H, nullptr);
        k_glu<1><<<ROWS, 256, 0, stream>>>(H, X, nullptr);
        // 3. Conv module: x += conv(x)
        k_ln<0><<<4096, 256, 0, stream>>>(X, B1, conv_ln_g + l*DD, conv_ln_b + l*DD, nullptr, 1e-5f);
        k_gemm<1><<<dim3(128, 8), 256, 0, stream>>>(B1, Wbn + (size_t)l*1024*DD, bneck_b + l*1024,
                                                    ROWS, 1024, DD, H, nullptr);
        k_glu<0><<<ROWS, 256, 0, stream>>>(H, nullptr, B2);
        k_dwconv<<<ROWS, 256, 0, stream>>>(B2, DWT + (size_t)l*31*DD, dw_b + l*DD, F0);
        k_ln<1><<<4096, 256, 0, stream>>>(F0, B1, conv_ln2_g + l*DD, conv_ln2_b + l*DD, nullptr, 1e-5f);
        k_gemm<3><<<dim3(128, 4), 256, 0, stream>>>(B1, Wcl + (size_t)l*DD*DD, conv_lin_b + l*DD,
                                                    ROWS, DD, DD, nullptr, X);
        // 4. FFN2 + norm2:  x = ln(x + 0.5*ffn(x))
        k_ln<0><<<4096, 256, 0, stream>>>(X, B1, ffn2_ln_g + l*DD, ffn2_ln_b + l*DD, nullptr, 1e-5f);
        k_gemm<0><<<dim3(128, 16), 256, 0, stream>>>(B1, Wf2a + (size_t)l*FF*DD, ffn2_b1 + l*FF,
                                                     ROWS, FF, DD, H, nullptr);
        k_gemm<4><<<dim3(128, 4), 256, 0, stream>>>(H, Wf2b + (size_t)l*DD*FF, ffn2_b2 + l*DD,
                                                    ROWS, DD, FF, F0, X);
        k_ln<2><<<4096, 256, 0, stream>>>(F0, X, norm2_g + l*DD, norm2_b + l*DD, nullptr, 1e-5f);
    }
    // final LN (eps 1e-6) + speaker broadcast
    k_ln<3><<<4096, 256, 0, stream>>>(X, d_out, final_g, final_b, speaker, 1e-6f);
}

// Round 2
// 3759.263 us; speedup vs baseline: 1.7485x; 1.7485x over previous
//
#include <hip/hip_runtime.h>
#include <hip/hip_bf16.h>
#include <stdint.h>

// ---------------------------------------------------------------------------
// S4 / Conformer-style encoder, 6 layers. B=8 T=2048 D=512 F=2048 N=64 K=31
// Residual stream x kept fp32 in ws; GEMMs in bf16 MFMA (16x16x32), fp32 acc.
// DSS via chunked linear recurrence: MFMA local-state GEMM + tiny chunk scan
// + per-h [Toeplitz | state-propagation] MFMA GEMM.  (R1's serial wave scan
// was 3.5ms latency-bound; this replaces it with ~5 GF of MFMA work.)
// ---------------------------------------------------------------------------

#define NL 6
#define TT 2048
#define BB 8
#define DD 512
#define FF 2048
#define ROWS (BB*TT)          // 16384

typedef __attribute__((ext_vector_type(4))) float f32x4;
typedef __attribute__((ext_vector_type(8))) short s16x8;

#define DEVI __device__ __forceinline__

DEVI float bf2f(uint32_t u) { union { uint32_t i; float f; } v; v.i = u << 16; return v.f; }
DEVI uint16_t f2bf(float f) {
    union { float f; uint32_t i; } v; v.f = f;
    uint32_t x = v.i;
    return (uint16_t)((x + 0x7fffu + ((x >> 16) & 1u)) >> 16);   // RNE
}
DEVI float gelu_f(float x) {   // tanh-approx gelu (jax.nn.gelu default)
    float x3 = x * x * x;
    float a  = 0.7978845608028654f * (x + 0.044715f * x3);
    float e  = __expf(2.0f * a);
    float t  = 1.0f - 2.0f / (e + 1.0f);
    return 0.5f * x * (1.0f + t);
}
DEVI float sigm(float x) { return 1.0f / (1.0f + __expf(-x)); }

// ---------------- weight prep ----------------------------------------------
// fp32 [L][K][N] -> bf16 [L][N][K]
__global__ void k_wtrans(const float* __restrict__ src, uint16_t* __restrict__ dst,
                         int K, int N) {
    __shared__ float tile[32][33];
    int l = blockIdx.z;
    const float* s = src + (size_t)l * K * N;
    uint16_t*    d = dst + (size_t)l * N * K;
    int n0 = blockIdx.x * 32, k0 = blockIdx.y * 32;
    int tx = threadIdx.x, ty = threadIdx.y;
#pragma unroll
    for (int i = 0; i < 4; i++) {
        int k = k0 + ty + i * 8;
        tile[ty + i * 8][tx] = s[(size_t)k * N + n0 + tx];
    }
    __syncthreads();
#pragma unroll
    for (int i = 0; i < 4; i++) {
        int n = n0 + ty + i * 8;
        d[(size_t)n * K + k0 + tx] = f2bf(tile[tx][ty + i * 8]);
    }
}
// fp32 -> bf16 same layout
__global__ void k_wcvt(const float* __restrict__ src, uint16_t* __restrict__ dst, int n) {
    int i = blockIdx.x * 256 + threadIdx.x;
    if (i < n) dst[i] = f2bf(src[i]);
}
// dw [L][512][31] -> dwt [L][31][512] fp32
__global__ void k_dwt(const float* __restrict__ dw, float* __restrict__ dwt) {
    int i = blockIdx.x * 256 + threadIdx.x;
    int tot = NL * DD * 31;
    if (i >= tot) return;
    int l = i / (DD * 31), r = i % (DD * 31), d = r / 31, k = r % 31;
    dwt[(size_t)l * 31 * DD + k * DD + d] = dw[i];
}

// ---------------- input projection  src[16384][80] @ W[80][512] -------------
__global__ void k_inproj(const float* __restrict__ src, const float* __restrict__ W,
                         const float* __restrict__ bias, float* __restrict__ X) {
    __shared__ float srow[80];
    int r = blockIdx.x, tid = threadIdx.x;
    if (tid < 80) srow[tid] = src[(size_t)r * 80 + tid];
    __syncthreads();
    int c = tid * 2;
    float a0 = bias[c], a1 = bias[c + 1];
    for (int k = 0; k < 80; k++) {
        float s = srow[k];
        const float2 w = *(const float2*)(W + (size_t)k * DD + c);
        a0 = fmaf(s, w.x, a0);
        a1 = fmaf(s, w.y, a1);
    }
    float2* px = (float2*)(X + (size_t)r * DD + c);
    *px = make_float2(a0, a1);
}

// ---------------- LayerNorm (wave per row, row = 512 f32) -------------------
// MODE 0: ->bf16   1: gelu->bf16   2: ->f32   3: ->f32 + speaker (final)
template <int MODE>
__global__ void k_ln(const float* __restrict__ in, void* __restrict__ outp,
                     const float* __restrict__ gam, const float* __restrict__ bet,
                     const float* __restrict__ spk, float eps) {
    int row  = blockIdx.x * 4 + (threadIdx.x >> 6);
    int lane = threadIdx.x & 63;
    const float* x = in + (size_t)row * DD;
    float4 a0 = *(const float4*)&x[lane * 4];
    float4 a1 = *(const float4*)&x[256 + lane * 4];
    float v[8] = {a0.x, a0.y, a0.z, a0.w, a1.x, a1.y, a1.z, a1.w};
    float s = 0.f, q = 0.f;
#pragma unroll
    for (int i = 0; i < 8; i++) { s += v[i]; q += v[i] * v[i]; }
#pragma unroll
    for (int m = 1; m < 64; m <<= 1) { s += __shfl_xor(s, m); q += __shfl_xor(q, m); }
    float mean = s * (1.0f / 512.0f);
    float var  = fmaxf(q * (1.0f / 512.0f) - mean * mean, 0.0f);
    float inv  = rsqrtf(var + eps);
    float4 g0 = *(const float4*)&gam[lane * 4];
    float4 g1 = *(const float4*)&gam[256 + lane * 4];
    float4 b0 = *(const float4*)&bet[lane * 4];
    float4 b1 = *(const float4*)&bet[256 + lane * 4];
    float gv[8] = {g0.x, g0.y, g0.z, g0.w, g1.x, g1.y, g1.z, g1.w};
    float bv[8] = {b0.x, b0.y, b0.z, b0.w, b1.x, b1.y, b1.z, b1.w};
    float y[8];
#pragma unroll
    for (int i = 0; i < 8; i++) y[i] = (v[i] - mean) * inv * gv[i] + bv[i];
    if (MODE == 1) {
#pragma unroll
        for (int i = 0; i < 8; i++) y[i] = gelu_f(y[i]);
    }
    if (MODE == 0 || MODE == 1) {
        uint16_t* o = (uint16_t*)outp + (size_t)row * DD;
        uint2 p0, p1;
        p0.x = (uint32_t)f2bf(y[0]) | ((uint32_t)f2bf(y[1]) << 16);
        p0.y = (uint32_t)f2bf(y[2]) | ((uint32_t)f2bf(y[3]) << 16);
        p1.x = (uint32_t)f2bf(y[4]) | ((uint32_t)f2bf(y[5]) << 16);
        p1.y = (uint32_t)f2bf(y[6]) | ((uint32_t)f2bf(y[7]) << 16);
        *(uint2*)&o[lane * 4]       = p0;
        *(uint2*)&o[256 + lane * 4] = p1;
    } else {
        float* o = (float*)outp + (size_t)row * DD;
        if (MODE == 3) {
            const float* sp = spk + (size_t)(row >> 11) * DD;
            float4 s0 = *(const float4*)&sp[lane * 4];
            float4 s1 = *(const float4*)&sp[256 + lane * 4];
            y[0] += s0.x; y[1] += s0.y; y[2] += s0.z; y[3] += s0.w;
            y[4] += s1.x; y[5] += s1.y; y[6] += s1.z; y[7] += s1.w;
        }
        *(float4*)&o[lane * 4]       = make_float4(y[0], y[1], y[2], y[3]);
        *(float4*)&o[256 + lane * 4] = make_float4(y[4], y[5], y[6], y[7]);
    }
}

// ---------------- bf16 MFMA GEMM, 128x128 tile, BK=32, 4 waves --------------
// A bf16 [M][K]; Bt bf16 [N][K]  (B transposed).  C = A @ Bt^T + bias.
// MODE 0: gelu->bf16 out[M][N]   1: ->bf16 out[M][N]
//      2: X[M][512] += 0.5*v     3: X += v       4: outf32 = X + 0.5*v
template <int MODE>
__global__ __launch_bounds__(256) void k_gemm(
    const uint16_t* __restrict__ A, const uint16_t* __restrict__ Bt,
    const float* __restrict__ bias, int M, int N, int K,
    void* __restrict__ outp, float* __restrict__ X) {
    __shared__ __align__(16) uint16_t As[128 * 40];
    __shared__ __align__(16) uint16_t Bs[128 * 40];
    int tid = threadIdx.x;
    int m0 = blockIdx.x * 128, n0 = blockIdx.y * 128;
    int wave = tid >> 6, lane = tid & 63;
    int wm = (wave >> 1) * 64, wn = (wave & 1) * 64;
    int l15 = lane & 15, l16 = lane >> 4;

    f32x4 acc[4][4];
#pragma unroll
    for (int i = 0; i < 4; i++)
#pragma unroll
        for (int j = 0; j < 4; j++) acc[i][j] = (f32x4){0.f, 0.f, 0.f, 0.f};

    for (int kt = 0; kt < K; kt += 32) {
#pragma unroll
        for (int i = 0; i < 2; i++) {
            int idx = tid + i * 256;
            int row = idx >> 2, kq = idx & 3;
            uint4 va = *(const uint4*)(A  + (size_t)(m0 + row) * K + kt + kq * 8);
            *(uint4*)&As[row * 40 + kq * 8] = va;
            uint4 vb = *(const uint4*)(Bt + (size_t)(n0 + row) * K + kt + kq * 8);
            *(uint4*)&Bs[row * 40 + kq * 8] = vb;
        }
        __syncthreads();
        s16x8 af[4], bfr[4];
#pragma unroll
        for (int i = 0; i < 4; i++)
            af[i] = *(const s16x8*)&As[(wm + i * 16 + l15) * 40 + l16 * 8];
#pragma unroll
        for (int j = 0; j < 4; j++)
            bfr[j] = *(const s16x8*)&Bs[(wn + j * 16 + l15) * 40 + l16 * 8];
#pragma unroll
        for (int i = 0; i < 4; i++)
#pragma unroll
            for (int j = 0; j < 4; j++)
                acc[i][j] = __builtin_amdgcn_mfma_f32_16x16x32_bf16(af[i], bfr[j], acc[i][j], 0, 0, 0);
        __syncthreads();
    }
    // epilogue: D frag: col = l15, row = l16*4 + q
#pragma unroll
    for (int i = 0; i < 4; i++) {
#pragma unroll
        for (int j = 0; j < 4; j++) {
            int gcol = n0 + wn + j * 16 + l15;
            float bv = bias[gcol];
#pragma unroll
            for (int q = 0; q < 4; q++) {
                int grow = m0 + wm + i * 16 + l16 * 4 + q;
                float v = acc[i][j][q] + bv;
                if (MODE == 0) {
                    ((uint16_t*)outp)[(size_t)grow * N + gcol] = f2bf(gelu_f(v));
                } else if (MODE == 1) {
                    ((uint16_t*)outp)[(size_t)grow * N + gcol] = f2bf(v);
                } else if (MODE == 2) {
                    X[(size_t)grow * DD + gcol] += 0.5f * v;
                } else if (MODE == 3) {
                    X[(size_t)grow * DD + gcol] += v;
                } else {
                    ((float*)outp)[(size_t)grow * DD + gcol] =
                        X[(size_t)grow * DD + gcol] + 0.5f * v;
                }
            }
        }
    }
}

// ---------------- bf16 transpose [R][C] -> [C][R] per batch z ---------------
__global__ void k_tpose(const uint16_t* __restrict__ in, uint16_t* __restrict__ out,
                        int R, int C) {
    __shared__ uint16_t tile[32][33];
    size_t boff = (size_t)blockIdx.z * R * C;
    int c0 = blockIdx.x * 32, r0 = blockIdx.y * 32;
    int tx = threadIdx.x, ty = threadIdx.y;
#pragma unroll
    for (int i = 0; i < 4; i++)
        tile[ty + i * 8][tx] = in[boff + (size_t)(r0 + ty + i * 8) * C + c0 + tx];
    __syncthreads();
#pragma unroll
    for (int i = 0; i < 4; i++)
        out[boff + (size_t)(c0 + ty + i * 8) * R + r0 + tx] = tile[tx][ty + i * 8];
}

// ===================== DSS chunked-scan machinery ===========================
// Recurrence: sigma[t] = A*sigma[t-1] + u[t],  y[t] = dt*Re(sum_n C_n sigma_n[t]).
// Chunk Lc=64, NC=32 chunks. Exact decomposition:
//   E_i  = sum_{s<64} A^{63-s} u[t0+s]              (pass1, MFMA: E = Phi*U)
//   S_0  = 0;  S_{i+1} = A^64 * S_i + E_i           (pass2, tiny scan)
//   y[t0+r] = sum_{c<=r} k[r-c]*u[t0+c] + d*u[t0+r]
//           + sum_n [Re(dt*C*A^{r+1})*SreN - Im(dt*C*A^{r+1})*SimN]
//     -> per-h GEMM  y = G_h [64x192] @ [u_chunk(64); Sre(64); Sim(64)]  (pass3)

// Phi[l]: [128][64] bf16 rows 0..63 Re(A_n^{63-s}), 64..127 Im.  A64f[l]: [64] cplx
__global__ __launch_bounds__(64) void k_phiprep(
        const float* __restrict__ lam_re, const float* __restrict__ lam_im,
        const float* __restrict__ log_dt, uint16_t* __restrict__ PHI,
        float* __restrict__ A64f) {
    int l = blockIdx.x, n = threadIdx.x;
    float dt = expf(log_dt[l]);
    float lr = lam_re[l * 64 + n], li = lam_im[l * 64 + n];
    float mag = expf(-expf(lr) * dt), th = li * dt;
    float Are = mag * __cosf(th), Aim = mag * __sinf(th);
    float Pre = 1.f, Pim = 0.f;
    uint16_t* ph = PHI + (size_t)l * 8192;
    for (int tau = 0; tau < 64; tau++) {
        int s = 63 - tau;
        ph[n * 64 + s]        = f2bf(Pre);
        ph[(64 + n) * 64 + s] = f2bf(Pim);
        float nr = Pre * Are - Pim * Aim;
        float ni = Pre * Aim + Pim * Are;
        Pre = nr; Pim = ni;
    }
    A64f[l * 128 + 2 * n]     = Pre;   // A^64
    A64f[l * 128 + 2 * n + 1] = Pim;
}

// G[h][64 r][192 k] bf16: cols 0..63 toeplitz k[r-c] (+d on diag); 64..127 Re-w; 128..191 -Im-w
__global__ __launch_bounds__(64) void k_gprep(
        const float* __restrict__ lam_re, const float* __restrict__ lam_im,
        const float* __restrict__ c_re, const float* __restrict__ c_im,
        const float* __restrict__ ssm_d, const float* __restrict__ log_dt,
        int l, uint16_t* __restrict__ G) {
    int h = blockIdx.x, n = threadIdx.x;
    __shared__ float klds[64];
    float dt = expf(log_dt[l]);
    float lr = lam_re[l * 64 + n], li = lam_im[l * 64 + n];
    float mag = expf(-expf(lr) * dt), th = li * dt;
    float Are = mag * __cosf(th), Aim = mag * __sinf(th);
    float Cre = c_re[(size_t)l * DD * 64 + h * 64 + n];
    float Cim = c_im[(size_t)l * DD * 64 + h * 64 + n];
    uint16_t* Gh = G + (size_t)h * 64 * 192;
    float Pre = 1.f, Pim = 0.f;                       // A^r
    for (int r = 0; r < 64; r++) {
        float t = Cre * Pre - Cim * Pim;              // Re(C*A^r)
        float s = t;
        s += __shfl_xor(s, 1);  s += __shfl_xor(s, 2);  s += __shfl_xor(s, 4);
        s += __shfl_xor(s, 8);  s += __shfl_xor(s, 16); s += __shfl_xor(s, 32);
        if (n == 0) klds[r] = dt * s;
        float nr = Pre * Are - Pim * Aim;             // A^{r+1}
        float ni = Pre * Aim + Pim * Are;
        float wre = dt * (Cre * nr - Cim * ni);
        float wim = dt * (Cre * ni + Cim * nr);
        Gh[r * 192 + 64 + n]  = f2bf(wre);
        Gh[r * 192 + 128 + n] = f2bf(-wim);
        Pre = nr; Pim = ni;
    }
    __syncthreads();
    float dh = ssm_d[l * DD + h];
    for (int r = 0; r < 64; r++) {
        int c = n;
        float val = (c < r) ? klds[r - c] : (c == r ? klds[0] + dh : 0.f);
        Gh[r * 192 + c] = f2bf(val);
    }
}

// pass1: E[col][128] = Phi[128x64] @ u-chunks.  col = bh*32 + i (131072 cols).
// u-chunk columns are contiguous 64-elem runs of u, loaded direct from global.
__global__ __launch_bounds__(256) void k_pass1(
        const uint16_t* __restrict__ u, const uint16_t* __restrict__ PHI,
        uint16_t* __restrict__ E) {
    __shared__ __align__(16) uint16_t Phs[128 * 72];
    int tid = threadIdx.x;
    for (int v = tid; v < 1024; v += 256) {
        int row = v >> 3, kb = v & 7;
        *(s16x8*)&Phs[row * 72 + kb * 8] = *(const s16x8*)&PHI[row * 64 + kb * 8];
    }
    __syncthreads();
    int wave = tid >> 6, lane = tid & 63;
    int l15 = lane & 15, l16 = lane >> 4;
    int m0 = (wave & 1) * 64;
    int colbase = blockIdx.x * 128 + (wave >> 1) * 64;
    f32x4 acc[4][4];
#pragma unroll
    for (int i = 0; i < 4; i++)
#pragma unroll
        for (int j = 0; j < 4; j++) acc[i][j] = (f32x4){0.f, 0.f, 0.f, 0.f};
#pragma unroll
    for (int kt = 0; kt < 64; kt += 32) {
        s16x8 a[4], b[4];
#pragma unroll
        for (int i = 0; i < 4; i++)
            a[i] = *(const s16x8*)&Phs[(m0 + i * 16 + l15) * 72 + kt + l16 * 8];
#pragma unroll
        for (int j = 0; j < 4; j++)
            b[j] = *(const s16x8*)(u + (size_t)(colbase + j * 16 + l15) * 64 + kt + l16 * 8);
#pragma unroll
        for (int i = 0; i < 4; i++)
#pragma unroll
            for (int j = 0; j < 4; j++)
                acc[i][j] = __builtin_amdgcn_mfma_f32_16x16x32_bf16(a[i], b[j], acc[i][j], 0, 0, 0);
    }
#pragma unroll
    for (int i = 0; i < 4; i++)
#pragma unroll
        for (int j = 0; j < 4; j++) {
            int col = colbase + j * 16 + l15;
            int r0  = m0 + i * 16 + l16 * 4;
            uint32_t p0 = (uint32_t)f2bf(acc[i][j][0]) | ((uint32_t)f2bf(acc[i][j][1]) << 16);
            uint32_t p1 = (uint32_t)f2bf(acc[i][j][2]) | ((uint32_t)f2bf(acc[i][j][3]) << 16);
            *(uint2*)&E[(size_t)col * 128 + r0] = make_uint2(p0, p1);
        }
}

// pass2: chunk-boundary states.  thread = (bh, n).  Sp[h][b*32+i][128]
__global__ void k_pass2(const uint16_t* __restrict__ E, const float* __restrict__ A64f,
                        int l, uint16_t* __restrict__ Sp) {
    int gid = blockIdx.x * 256 + threadIdx.x;   // 262144
    int n = gid & 63, bh = gid >> 6;            // bh = b*512 + h
    int b = bh >> 9, h = bh & 511;
    float2 A = *(const float2*)&A64f[l * 128 + 2 * n];
    float Sre = 0.f, Sim = 0.f;
    const uint16_t* Eb = E + (size_t)bh * 32 * 128;
    uint16_t* So = Sp + (size_t)h * 32768 + (size_t)b * 32 * 128;
    for (int i = 0; i < 32; i++) {
        So[i * 128 + n]      = f2bf(Sre);
        So[i * 128 + 64 + n] = f2bf(Sim);
        float er = bf2f((uint32_t)Eb[i * 128 + n]);
        float ei = bf2f((uint32_t)Eb[i * 128 + 64 + n]);
        float nr = A.x * Sre - A.y * Sim + er;
        float ni = A.x * Sim + A.y * Sre + ei;
        Sre = nr; Sim = ni;
    }
}

// pass3: per-h GEMM  Y[64 x 256cols] = G_h[64x192] @ [u;Sre;Sim].  block = h.
__global__ __launch_bounds__(256) void k_pass3(
        const uint16_t* __restrict__ G, const uint16_t* __restrict__ u,
        const uint16_t* __restrict__ Sp, uint16_t* __restrict__ Y) {
    __shared__ __align__(16) uint16_t Gs[64 * 200];
    int h = blockIdx.x, tid = threadIdx.x;
    for (int v = tid; v < 1536; v += 256) {
        int row = v / 24, kb = v % 24;
        *(s16x8*)&Gs[row * 200 + kb * 8] = *(const s16x8*)&G[(size_t)h * 12288 + row * 192 + kb * 8];
    }
    __syncthreads();
    int wave = tid >> 6, lane = tid & 63;
    int l15 = lane & 15, l16 = lane >> 4;
    int wn = wave * 64;
    const uint16_t* uh = u + (size_t)h * TT;
    const uint16_t* sh = Sp + (size_t)h * 32768;
    f32x4 acc[4][4];
#pragma unroll
    for (int i = 0; i < 4; i++)
#pragma unroll
        for (int j = 0; j < 4; j++) acc[i][j] = (f32x4){0.f, 0.f, 0.f, 0.f};
#pragma unroll
    for (int kt = 0; kt < 192; kt += 32) {
        s16x8 a[4], b[4];
#pragma unroll
        for (int i = 0; i < 4; i++)
            a[i] = *(const s16x8*)&Gs[(i * 16 + l15) * 200 + kt + l16 * 8];
#pragma unroll
        for (int j = 0; j < 4; j++) {
            int col = wn + j * 16 + l15;           // (b<<5) | chunk
            const uint16_t* src;
            if (kt < 64)
                src = uh + (size_t)(col >> 5) * (DD * TT) + (col & 31) * 64 + kt + l16 * 8;
            else
                src = sh + (size_t)col * 128 + (kt - 64) + l16 * 8;
            b[j] = *(const s16x8*)src;
        }
#pragma unroll
        for (int i = 0; i < 4; i++)
#pragma unroll
            for (int j = 0; j < 4; j++)
                acc[i][j] = __builtin_amdgcn_mfma_f32_16x16x32_bf16(a[i], b[j], acc[i][j], 0, 0, 0);
    }
#pragma unroll
    for (int i = 0; i < 4; i++)
#pragma unroll
        for (int j = 0; j < 4; j++) {
            int col = wn + j * 16 + l15;
            int r0  = i * 16 + l16 * 4;
            uint16_t* dst = Y + (size_t)(col >> 5) * (DD * TT) + (size_t)h * TT + (col & 31) * 64 + r0;
            uint32_t p0 = (uint32_t)f2bf(acc[i][j][0]) | ((uint32_t)f2bf(acc[i][j][1]) << 16);
            uint32_t p1 = (uint32_t)f2bf(acc[i][j][2]) | ((uint32_t)f2bf(acc[i][j][3]) << 16);
            *(uint2*)&dst[0] = make_uint2(p0, p1);
        }
}

// ---------------- gelu + transpose [b][h][t] -> [b][t][h]  (d*u folded in G)
__global__ void k_tgelu(const uint16_t* __restrict__ y, uint16_t* __restrict__ out) {
    __shared__ uint16_t tile[32][33];
    int b = blockIdx.z;
    int t0 = blockIdx.x * 32, h0 = blockIdx.y * 32;
    int tx = threadIdx.x, ty = threadIdx.y;
    const uint16_t* yb = y + (size_t)b * DD * TT;
#pragma unroll
    for (int i = 0; i < 4; i++) {
        int h = h0 + ty + i * 8;
        tile[ty + i * 8][tx] = f2bf(gelu_f(bf2f((uint32_t)yb[(size_t)h * TT + t0 + tx])));
    }
    __syncthreads();
    uint16_t* ob = out + (size_t)b * TT * DD;
#pragma unroll
    for (int i = 0; i < 4; i++) {
        int t = t0 + ty + i * 8;
        ob[(size_t)t * DD + h0 + tx] = tile[tx][ty + i * 8];
    }
}

// ---------------- GLU: z[16384][1024] -> a*sig(g); SKIP: X += ; else bf16 out
template <int SKIP>
__global__ void k_glu(const uint16_t* __restrict__ z, float* __restrict__ X,
                      uint16_t* __restrict__ out) {
    int i = blockIdx.x * 256 + threadIdx.x;      // over 16384*256  (2 cols each)
    int r = i >> 8;
    int c = (i & 255) * 2;
    uint32_t av = *(const uint32_t*)&z[(size_t)r * 1024 + c];
    uint32_t gv = *(const uint32_t*)&z[(size_t)r * 1024 + 512 + c];
    float a0 = bf2f(av & 0xffffu), a1 = bf2f(av >> 16);
    float g0 = bf2f(gv & 0xffffu), g1 = bf2f(gv >> 16);
    float v0 = a0 * sigm(g0), v1 = a1 * sigm(g1);
    if (SKIP) {
        float2* px = (float2*)&X[(size_t)r * DD + c];
        float2 x = *px;
        x.x += v0; x.y += v1;
        *px = x;
    } else {
        uint32_t p = (uint32_t)f2bf(v0) | ((uint32_t)f2bf(v1) << 16);
        *(uint32_t*)&out[(size_t)r * DD + c] = p;
    }
}

// ---------------- depthwise conv k=31 SAME over t, [B][T][512] --------------
__global__ void k_dwconv(const uint16_t* __restrict__ in, const float* __restrict__ dwt,
                         const float* __restrict__ db, float* __restrict__ out) {
    int i = blockIdx.x * 256 + threadIdx.x;      // over 8*2048*256 (2 ch each)
    int d = (i & 255) * 2;
    int t = (i >> 8) & (TT - 1);
    int b = i >> 19;
    float a0 = db[d], a1 = db[d + 1];
    const uint16_t* ib = in + (size_t)b * TT * DD;
#pragma unroll
    for (int j = 0; j < 31; j++) {
        int tj = t + j - 15;
        if (tj >= 0 && tj < TT) {
            uint32_t v = *(const uint32_t*)&ib[(size_t)tj * DD + d];
            float2 w = *(const float2*)&dwt[j * DD + d];
            a0 = fmaf(bf2f(v & 0xffffu), w.x, a0);
            a1 = fmaf(bf2f(v >> 16), w.y, a1);
        }
    }
    size_t off = ((size_t)b * TT + t) * DD + d;
    *(float2*)&out[off] = make_float2(a0, a1);
}

// ---------------------------------------------------------------------------
extern "C" void kernel_launch(void* const* d_in, const int* in_sizes, int n_in,
                              void* d_out, int out_size, void* d_ws, size_t ws_size,
                              hipStream_t stream) {
    const float* src        = (const float*)d_in[0];
    const float* speaker    = (const float*)d_in[1];
    const float* src_w      = (const float*)d_in[2];
    const float* src_b      = (const float*)d_in[3];
    const float* ffn1_ln_g  = (const float*)d_in[4];
    const float* ffn1_ln_b  = (const float*)d_in[5];
    const float* ffn1_w1    = (const float*)d_in[6];
    const float* ffn1_b1    = (const float*)d_in[7];
    const float* ffn1_w2    = (const float*)d_in[8];
    const float* ffn1_b2    = (const float*)d_in[9];
    const float* norm1_g    = (const float*)d_in[10];
    const float* norm1_b    = (const float*)d_in[11];
    const float* lam_re     = (const float*)d_in[12];
    const float* lam_im     = (const float*)d_in[13];
    const float* c_re       = (const float*)d_in[14];
    const float* c_im       = (const float*)d_in[15];
    const float* ssm_d      = (const float*)d_in[16];
    const float* log_dt     = (const float*)d_in[17];
    const float* dss_out_w  = (const float*)d_in[18];
    const float* dss_out_b  = (const float*)d_in[19];
    const float* conv_ln_g  = (const float*)d_in[20];
    const float* conv_ln_b  = (const float*)d_in[21];
    const float* bneck_w    = (const float*)d_in[22];
    const float* bneck_b    = (const float*)d_in[23];
    const float* dw_w       = (const float*)d_in[24];
    const float* dw_b       = (const float*)d_in[25];
    const float* conv_ln2_g = (const float*)d_in[26];
    const float* conv_ln2_b = (const float*)d_in[27];
    const float* conv_lin_w = (const float*)d_in[28];
    const float* conv_lin_b = (const float*)d_in[29];
    const float* ffn2_ln_g  = (const float*)d_in[30];
    const float* ffn2_ln_b  = (const float*)d_in[31];
    const float* ffn2_w1    = (const float*)d_in[32];
    const float* ffn2_b1    = (const float*)d_in[33];
    const float* ffn2_w2    = (const float*)d_in[34];
    const float* ffn2_b2    = (const float*)d_in[35];
    const float* norm2_g    = (const float*)d_in[36];
    const float* norm2_b    = (const float*)d_in[37];
    const float* final_g    = (const float*)d_in[38];
    const float* final_b    = (const float*)d_in[39];
    (void)in_sizes; (void)n_in; (void)out_size; (void)ws_size;

    // workspace layout (bytes)
    uint8_t* ws = (uint8_t*)d_ws;
    float*    X   = (float*)   (ws + 0);                     // 33554432  f32 [16384][512]
    float*    F0  = (float*)   (ws + 33554432);              // 33554432  f32 [16384][512] / Spack bf16 [512][256][128]
    uint16_t* B1  = (uint16_t*)(ws + 67108864);              // 16777216  bf16 [16384][512] / G bf16 [512][64][192]
    uint16_t* B2  = (uint16_t*)(ws + 83886080);              // 16777216  bf16 [B][512][2048] (u) / [16384][512]
    uint16_t* B3  = (uint16_t*)(ws + 100663296);             // 16777216  bf16 [B][512][2048] (y)
    uint16_t* H   = (uint16_t*)(ws + 117440512);             // 67108864  bf16 GEMM mids / E bf16 [131072][128]
    uint16_t* Wf1a= (uint16_t*)(ws + 184549376);             // [L][2048][512]
    uint16_t* Wf1b= (uint16_t*)(ws + 197132288);             // [L][512][2048]
    uint16_t* Wds = (uint16_t*)(ws + 209715200);             // [L][1024][512]
    uint16_t* Wbn = (uint16_t*)(ws + 216006656);             // [L][1024][512]
    uint16_t* Wcl = (uint16_t*)(ws + 222298112);             // [L][512][512]
    uint16_t* Wf2a= (uint16_t*)(ws + 225443840);             // [L][2048][512]
    uint16_t* Wf2b= (uint16_t*)(ws + 238026752);             // [L][512][2048]
    float*    DWT = (float*)   (ws + 250609664);             // [L][31][512] f32 (380928 B)
    uint16_t* PHI = (uint16_t*)(ws + 250990592);             // [L][128][64] bf16 (98304 B)
    float*    A64f= (float*)   (ws + 251088896);             // [L][64][2] f32 (3072 B)

    uint16_t* GBUF = B1;                                     // per-layer G (12.6 MB <= 16.8)
    uint16_t* SPK  = (uint16_t*)F0;                          // per-layer chunk states
    uint16_t* EBUF = H;                                      // per-layer E (33.5 MB <= 67)

    dim3 tb(32, 8);
    // ---- weight prep (once per launch; deterministic) ----
    k_wtrans<<<dim3(FF/32, DD/32, NL), tb, 0, stream>>>(ffn1_w1, Wf1a, DD, FF);
    k_wtrans<<<dim3(DD/32, FF/32, NL), tb, 0, stream>>>(ffn1_w2, Wf1b, FF, DD);
    k_wtrans<<<dim3(1024/32, DD/32, NL), tb, 0, stream>>>(dss_out_w, Wds, DD, 1024);
    k_wcvt<<<(NL*1024*DD + 255)/256, 256, 0, stream>>>(bneck_w, Wbn, NL*1024*DD);
    k_wcvt<<<(NL*DD*DD + 255)/256, 256, 0, stream>>>(conv_lin_w, Wcl, NL*DD*DD);
    k_wtrans<<<dim3(FF/32, DD/32, NL), tb, 0, stream>>>(ffn2_w1, Wf2a, DD, FF);
    k_wtrans<<<dim3(DD/32, FF/32, NL), tb, 0, stream>>>(ffn2_w2, Wf2b, FF, DD);
    k_dwt<<<(NL*DD*31 + 255)/256, 256, 0, stream>>>(dw_w, DWT);
    k_phiprep<<<NL, 64, 0, stream>>>(lam_re, lam_im, log_dt, PHI, A64f);

    // ---- input projection ----
    k_inproj<<<ROWS, 256, 0, stream>>>(src, src_w, src_b, X);

    for (int l = 0; l < NL; l++) {
        // 1. FFN1: x += 0.5 * ffn(x)
        k_ln<0><<<4096, 256, 0, stream>>>(X, B1, ffn1_ln_g + l*DD, ffn1_ln_b + l*DD, nullptr, 1e-5f);
        k_gemm<0><<<dim3(128, 16), 256, 0, stream>>>(B1, Wf1a + (size_t)l*FF*DD, ffn1_b1 + l*FF,
                                                     ROWS, FF, DD, H, nullptr);
        k_gemm<2><<<dim3(128, 4), 256, 0, stream>>>(H, Wf1b + (size_t)l*DD*FF, ffn1_b2 + l*DD,
                                                    ROWS, DD, FF, nullptr, X);
        // 2. DSS:  skip = x;  x = glu(dss(ln(x))) + skip
        k_ln<0><<<4096, 256, 0, stream>>>(X, B1, norm1_g + l*DD, norm1_b + l*DD, nullptr, 1e-5f);
        k_tpose<<<dim3(DD/32, TT/32, BB), tb, 0, stream>>>(B1, B2, TT, DD);     // u [B][512][2048]
        k_gprep<<<DD, 64, 0, stream>>>(lam_re, lam_im, c_re, c_im, ssm_d, log_dt, l, GBUF);
        k_pass1<<<1024, 256, 0, stream>>>(B2, PHI + (size_t)l*8192, EBUF);
        k_pass2<<<1024, 256, 0, stream>>>(EBUF, A64f, l, SPK);
        k_pass3<<<DD, 256, 0, stream>>>(GBUF, B2, SPK, B3);
        k_tgelu<<<dim3(TT/32, DD/32, BB), tb, 0, stream>>>(B3, B1);
        k_gemm<1><<<dim3(128, 8), 256, 0, stream>>>(B1, Wds + (size_t)l*1024*DD, dss_out_b + l*1024,
                                                    ROWS, 1024, DD, H, nullptr);
        k_glu<1><<<ROWS, 256, 0, stream>>>(H, X, nullptr);
        // 3. Conv module: x += conv(x)
        k_ln<0><<<4096, 256, 0, stream>>>(X, B1, conv_ln_g + l*DD, conv_ln_b + l*DD, nullptr, 1e-5f);
        k_gemm<1><<<dim3(128, 8), 256, 0, stream>>>(B1, Wbn + (size_t)l*1024*DD, bneck_b + l*1024,
                                                    ROWS, 1024, DD, H, nullptr);
        k_glu<0><<<ROWS, 256, 0, stream>>>(H, nullptr, B2);
        k_dwconv<<<ROWS, 256, 0, stream>>>(B2, DWT + (size_t)l*31*DD, dw_b + l*DD, F0);
        k_ln<1><<<4096, 256, 0, stream>>>(F0, B1, conv_ln2_g + l*DD, conv_ln2_b + l*DD, nullptr, 1e-5f);
        k_gemm<3><<<dim3(128, 4), 256, 0, stream>>>(B1, Wcl + (size_t)l*DD*DD, conv_lin_b + l*DD,
                                                    ROWS, DD, DD, nullptr, X);
        // 4. FFN2 + norm2:  x = ln(x + 0.5*ffn(x))
        k_ln<0><<<4096, 256, 0, stream>>>(X, B1, ffn2_ln_g + l*DD, ffn2_ln_b + l*DD, nullptr, 1e-5f);
        k_gemm<0><<<dim3(128, 16), 256, 0, stream>>>(B1, Wf2a + (size_t)l*FF*DD, ffn2_b1 + l*FF,
                                                     ROWS, FF, DD, H, nullptr);
        k_gemm<4><<<dim3(128, 4), 256, 0, stream>>>(H, Wf2b + (size_t)l*DD*FF, ffn2_b2 + l*DD,
                                                    ROWS, DD, FF, F0, X);
        k_ln<2><<<4096, 256, 0, stream>>>(F0, X, norm2_g + l*DD, norm2_b + l*DD, nullptr, 1e-5f);
    }
    // final LN (eps 1e-6) + speaker broadcast
    k_ln<3><<<4096, 256, 0, stream>>>(X, d_out, final_g, final_b, speaker, 1e-6f);
}